// Round 6
// baseline (150.876 us; speedup 1.0000x reference)
//
#include <hip/hip_runtime.h>
#include <math.h>

// Exact IIR reformulation of the 181-tap bi-exponential FIR (see R3-R5).
//   out[n]*scale = r1*(S1[m] - r1^181*S1[m-181]) - r2*S2[m],  m = n+180
//   S[m] = r*S[m-1] + u[m], state zeroed at segment input start.
// R6: ONE chunk per wave (16 elems/lane, 1024 staged = L+W exactly).
//  - single cross-lane scan (serial DS depth halved vs R5's 2 chunks)
//  - no chunk carries, no prev-chunk oct: 181-delay fully in-chunk,
//    d = 0 for e < 181 is exact (S1 state before segment start is 0)
//  - DS ops/wave 44 -> 26 per 1024 elems; scan truncation: S1 drops d=32
//    (r1^512 = 3.9e-8), S2 keeps d=1,2,4 (dropped r2^128 = 7.6e-12)

namespace {
constexpr int kB   = 1000;
constexpr int kT   = 20000;
constexpr int kInW = kT + 180;       // 20180
constexpr int W    = 180;            // warm-up inputs = taps-1
constexpr int L    = 844;            // outputs per segment; L+W = 1024 staged exactly
constexpr int SEGS = 24;             // 24*844 = 20256 >= 20000
}

struct Coefs {
  float r1e[16], r2e[16];    // r^j, j=0..15 (SGPR-resident kernarg)
  float s1c[5];              // r1^{16*2^i}, i=0..4 (d=32 dropped)
  float s2c[3];              // r2^{16*2^i}, i=0..2
  float A1, A1d, A2;         // r1/scale, r1^182/scale, r2/scale
};

__global__ __launch_bounds__(256, 6)
void biexp_iir_scan(const float* __restrict__ u, float* __restrict__ out, Coefs cf) {
  const int lane = threadIdx.x & 63;
  const int seg  = (blockIdx.x << 2) | (threadIdx.x >> 6);   // 0..23
  const int row  = blockIdx.y;
  const int n0   = seg * L;                                  // input base = output base
  const int nend = (n0 + L < kT) ? n0 + L : kT;
  const int lim  = nend - n0 + W;                            // exclusive staged-store bound (mult of 4)
  const float* ur = u + (size_t)row * kInW;
  float* outr = out + (size_t)row * kT;

  // ---- all 4 float4 loads issued at entry (16 elems/lane, full MLP)
  // Clamp is 16-elem-granular: a lane is either fully valid or fully OOB
  // (kInW - n0 is a multiple of 16 only for the last seg where it = lim = 768;
  // clamped lanes' garbage lands at staged e >= lim -> stores masked, and
  // only propagates upward through the scan to equally-masked lanes).
  int cb = n0 + 16 * lane;
  cb = cb < (kInW - 16) ? cb : (kInW - 16);
  const float4 q0 = *(const float4*)(ur + cb);
  const float4 q1 = *(const float4*)(ur + cb + 4);
  const float4 q2 = *(const float4*)(ur + cb + 8);
  const float4 q3 = *(const float4*)(ur + cb + 12);

  const float ux[16] = {q0.x, q0.y, q0.z, q0.w, q1.x, q1.y, q1.z, q1.w,
                        q2.x, q2.y, q2.z, q2.w, q3.x, q3.y, q3.z, q3.w};

  // ---- in-lane inclusive prefixes (two independent chains, interleaved)
  float p1[16], p2[16];
  p1[0] = ux[0]; p2[0] = ux[0];
  #pragma unroll
  for (int j = 1; j < 16; ++j) {
    p1[j] = fmaf(cf.r1e[1], p1[j-1], ux[j]);
    p2[j] = fmaf(cf.r2e[1], p2[j-1], ux[j]);
  }

  // ---- cross-lane Hillis scan on lane totals (S1: d=1..16, S2: d=1..4)
  float S1 = p1[15], S2 = p2[15], t;
  t = __shfl_up(S1, 1);  S1 = lane >= 1  ? fmaf(cf.s1c[0], t, S1) : S1;
  t = __shfl_up(S2, 1);  S2 = lane >= 1  ? fmaf(cf.s2c[0], t, S2) : S2;
  t = __shfl_up(S1, 2);  S1 = lane >= 2  ? fmaf(cf.s1c[1], t, S1) : S1;
  t = __shfl_up(S2, 2);  S2 = lane >= 2  ? fmaf(cf.s2c[1], t, S2) : S2;
  t = __shfl_up(S1, 4);  S1 = lane >= 4  ? fmaf(cf.s1c[2], t, S1) : S1;
  t = __shfl_up(S2, 4);  S2 = lane >= 4  ? fmaf(cf.s2c[2], t, S2) : S2;
  t = __shfl_up(S1, 8);  S1 = lane >= 8  ? fmaf(cf.s1c[3], t, S1) : S1;
  t = __shfl_up(S1, 16); S1 = lane >= 16 ? fmaf(cf.s1c[4], t, S1) : S1;
  // dropped: S1 d=32 (r1^512=3.9e-8), S2 d>=8 (r2^128=7.6e-12) -- << fp32 eps

  float X1 = __shfl_up(S1, 1); X1 = (lane == 0) ? 0.f : X1;   // exclusive lane-scan
  float X2 = __shfl_up(S2, 1); X2 = (lane == 0) ? 0.f : X2;
  const float H1 = cf.r1e[1] * X1;     // r * (state at end of prev lane)
  const float H2 = cf.r2e[1] * X2;

  // ---- full states at elem e = 16*lane + j (overwrite prefixes in place)
  float s1[16], s2[16];
  #pragma unroll
  for (int j = 0; j < 16; ++j) {
    s1[j] = fmaf(cf.r1e[j], H1, p1[j]);
    s2[j] = fmaf(cf.r2e[j], H2, p2[j]);
  }

  // ---- delayed state S1[e-181]: 181 = 11*16 + 5
  //   j>=5: slot j-5,  lane-11;  j<5: slot j+11, lane-12;  e<181 -> 0 (exact)
  float y[16];
  #pragma unroll
  for (int j = 0; j < 16; ++j) {
    const int slot = (j >= 5) ? j - 5 : j + 11;
    const int rot  = (j >= 5) ? 11 : 12;
    const float zz = __shfl(s1[slot], (lane - rot) & 63);
    const float d  = (lane >= rot) ? zz : 0.f;
    y[j] = fmaf(-cf.A2, s2[j], fmaf(-cf.A1d, d, cf.A1 * s1[j]));
  }

  // ---- stores: 4 float4, masks f4-uniform (W, lim mult of 4)
  const int off0 = 16 * lane;
  float* op = outr + (n0 - W + off0);
  #pragma unroll
  for (int q = 0; q < 4; ++q) {
    const int off = off0 + 4 * q;
    if (off >= W && off < lim) {
      float4 v;
      v.x = y[4*q+0]; v.y = y[4*q+1]; v.z = y[4*q+2]; v.w = y[4*q+3];
      *(float4*)(op + 4 * q) = v;
    }
  }
}

extern "C" void kernel_launch(void* const* d_in, const int* in_sizes, int n_in,
                              void* d_out, int out_size, void* d_ws, size_t ws_size,
                              hipStream_t stream) {
  const float* u = (const float*)d_in[0];
  float* out = (float*)d_out;

  const double r1 = exp(-1.0 / 30.0);
  const double r2 = exp(-1.0 / 5.0);
  const double scale = pow(6.0, -5.0 / 25.0) - pow(6.0, -30.0 / 25.0);

  Coefs cf;
  for (int j = 0; j < 16; ++j) {
    cf.r1e[j] = (float)pow(r1, (double)j);
    cf.r2e[j] = (float)pow(r2, (double)j);
  }
  for (int i = 0; i < 5; ++i) cf.s1c[i] = (float)pow(r1, (double)(16 << i));
  for (int i = 0; i < 3; ++i) cf.s2c[i] = (float)pow(r2, (double)(16 << i));
  cf.A1  = (float)(r1 / scale);
  cf.A1d = (float)(pow(r1, 182.0) / scale);
  cf.A2  = (float)(r2 / scale);

  hipLaunchKernelGGL(biexp_iir_scan, dim3(SEGS / 4, kB), dim3(256, 1, 1), 0, stream,
                     u, out, cf);
}

// Round 7
// 150.560 us; speedup vs baseline: 1.0021x; 1.0021x over previous
//
#include <hip/hip_runtime.h>
#include <math.h>

// Exact IIR reformulation of the 181-tap bi-exponential FIR (see R3-R6).
//   out[n]*scale = r1*(S1[m] - r1^181*S1[m-181]) - r2*S2[m],  m = n+180
//   S[m] = r*S[m-1] + u[m], state zeroed at segment input start.
// R7 = R6 core (1 chunk/wave, 16 elems/lane, no carries, 26 DS ops) with
// __launch_bounds__(256, 8): R6 compiled to VGPR=32, so 8 waves/SIMD is free
// -- R6's launch_bounds(256,6) was leaving 25% residency unused.

namespace {
constexpr int kB   = 1000;
constexpr int kT   = 20000;
constexpr int kInW = kT + 180;       // 20180
constexpr int W    = 180;            // warm-up inputs = taps-1
constexpr int L    = 844;            // outputs per segment; L+W = 1024 staged exactly
constexpr int SEGS = 24;             // 24*844 = 20256 >= 20000
}

struct Coefs {
  float r1e[16], r2e[16];    // r^j, j=0..15 (SGPR-resident kernarg)
  float s1c[5];              // r1^{16*2^i}, i=0..4 (d=32 dropped)
  float s2c[3];              // r2^{16*2^i}, i=0..2
  float A1, A1d, A2;         // r1/scale, r1^182/scale, r2/scale
};

__global__ __launch_bounds__(256, 8)   // VGPR=32 -> full 8 waves/SIMD residency
void biexp_iir_scan(const float* __restrict__ u, float* __restrict__ out, Coefs cf) {
  const int lane = threadIdx.x & 63;
  const int seg  = (blockIdx.x << 2) | (threadIdx.x >> 6);   // 0..23
  const int row  = blockIdx.y;
  const int n0   = seg * L;                                  // input base = output base
  const int nend = (n0 + L < kT) ? n0 + L : kT;
  const int lim  = nend - n0 + W;                            // exclusive staged-store bound (mult of 4)
  const float* ur = u + (size_t)row * kInW;
  float* outr = out + (size_t)row * kT;

  // ---- all 4 float4 loads issued at entry (16 elems/lane, full MLP)
  // Clamped lanes' garbage lands at staged e >= lim -> stores masked; it only
  // propagates upward through the scan to equally-masked lanes.
  int cb = n0 + 16 * lane;
  cb = cb < (kInW - 16) ? cb : (kInW - 16);
  const float4 q0 = *(const float4*)(ur + cb);
  const float4 q1 = *(const float4*)(ur + cb + 4);
  const float4 q2 = *(const float4*)(ur + cb + 8);
  const float4 q3 = *(const float4*)(ur + cb + 12);

  const float ux[16] = {q0.x, q0.y, q0.z, q0.w, q1.x, q1.y, q1.z, q1.w,
                        q2.x, q2.y, q2.z, q2.w, q3.x, q3.y, q3.z, q3.w};

  // ---- in-lane inclusive prefixes (two independent chains, interleaved)
  float p1[16], p2[16];
  p1[0] = ux[0]; p2[0] = ux[0];
  #pragma unroll
  for (int j = 1; j < 16; ++j) {
    p1[j] = fmaf(cf.r1e[1], p1[j-1], ux[j]);
    p2[j] = fmaf(cf.r2e[1], p2[j-1], ux[j]);
  }

  // ---- cross-lane Hillis scan on lane totals (S1: d=1..16, S2: d=1..4)
  float S1 = p1[15], S2 = p2[15], t;
  t = __shfl_up(S1, 1);  S1 = lane >= 1  ? fmaf(cf.s1c[0], t, S1) : S1;
  t = __shfl_up(S2, 1);  S2 = lane >= 1  ? fmaf(cf.s2c[0], t, S2) : S2;
  t = __shfl_up(S1, 2);  S1 = lane >= 2  ? fmaf(cf.s1c[1], t, S1) : S1;
  t = __shfl_up(S2, 2);  S2 = lane >= 2  ? fmaf(cf.s2c[1], t, S2) : S2;
  t = __shfl_up(S1, 4);  S1 = lane >= 4  ? fmaf(cf.s1c[2], t, S1) : S1;
  t = __shfl_up(S2, 4);  S2 = lane >= 4  ? fmaf(cf.s2c[2], t, S2) : S2;
  t = __shfl_up(S1, 8);  S1 = lane >= 8  ? fmaf(cf.s1c[3], t, S1) : S1;
  t = __shfl_up(S1, 16); S1 = lane >= 16 ? fmaf(cf.s1c[4], t, S1) : S1;
  // dropped: S1 d=32 (r1^512=3.9e-8), S2 d>=8 (r2^128=7.6e-12) -- << fp32 eps

  float X1 = __shfl_up(S1, 1); X1 = (lane == 0) ? 0.f : X1;   // exclusive lane-scan
  float X2 = __shfl_up(S2, 1); X2 = (lane == 0) ? 0.f : X2;
  const float H1 = cf.r1e[1] * X1;     // r * (state at end of prev lane)
  const float H2 = cf.r2e[1] * X2;

  // ---- full states at elem e = 16*lane + j
  float s1[16], s2[16];
  #pragma unroll
  for (int j = 0; j < 16; ++j) {
    s1[j] = fmaf(cf.r1e[j], H1, p1[j]);
    s2[j] = fmaf(cf.r2e[j], H2, p2[j]);
  }

  // ---- delayed state S1[e-181]: 181 = 11*16 + 5
  //   j>=5: slot j-5,  lane-11;  j<5: slot j+11, lane-12;  e<181 -> 0 (exact)
  float y[16];
  #pragma unroll
  for (int j = 0; j < 16; ++j) {
    const int slot = (j >= 5) ? j - 5 : j + 11;
    const int rot  = (j >= 5) ? 11 : 12;
    const float zz = __shfl(s1[slot], (lane - rot) & 63);
    const float d  = (lane >= rot) ? zz : 0.f;
    y[j] = fmaf(-cf.A2, s2[j], fmaf(-cf.A1d, d, cf.A1 * s1[j]));
  }

  // ---- stores: 4 float4, masks f4-uniform (W, lim mult of 4)
  const int off0 = 16 * lane;
  float* op = outr + (n0 - W + off0);
  #pragma unroll
  for (int q = 0; q < 4; ++q) {
    const int off = off0 + 4 * q;
    if (off >= W && off < lim) {
      float4 v;
      v.x = y[4*q+0]; v.y = y[4*q+1]; v.z = y[4*q+2]; v.w = y[4*q+3];
      *(float4*)(op + 4 * q) = v;
    }
  }
}

extern "C" void kernel_launch(void* const* d_in, const int* in_sizes, int n_in,
                              void* d_out, int out_size, void* d_ws, size_t ws_size,
                              hipStream_t stream) {
  const float* u = (const float*)d_in[0];
  float* out = (float*)d_out;

  const double r1 = exp(-1.0 / 30.0);
  const double r2 = exp(-1.0 / 5.0);
  const double scale = pow(6.0, -5.0 / 25.0) - pow(6.0, -30.0 / 25.0);

  Coefs cf;
  for (int j = 0; j < 16; ++j) {
    cf.r1e[j] = (float)pow(r1, (double)j);
    cf.r2e[j] = (float)pow(r2, (double)j);
  }
  for (int i = 0; i < 5; ++i) cf.s1c[i] = (float)pow(r1, (double)(16 << i));
  for (int i = 0; i < 3; ++i) cf.s2c[i] = (float)pow(r2, (double)(16 << i));
  cf.A1  = (float)(r1 / scale);
  cf.A1d = (float)(pow(r1, 182.0) / scale);
  cf.A2  = (float)(r2 / scale);

  hipLaunchKernelGGL(biexp_iir_scan, dim3(SEGS / 4, kB), dim3(256, 1, 1), 0, stream,
                     u, out, cf);
}